// Round 1
// baseline (167.320 us; speedup 1.0000x reference)
//
#include <hip/hip_runtime.h>
#include <hip/hip_bf16.h>
#include <stdint.h>

#define EPSBN 1e-5f

typedef float f32x4 __attribute__((ext_vector_type(4)));
typedef __bf16 bf16x8 __attribute__((ext_vector_type(8)));

#define BB 8
#define XCH 1024
#define YCH 512
#define CCH 512
#define PP  4096   // H*W = 64*64

__device__ __forceinline__ unsigned short f2bf(float f) {
    union { float f; uint32_t u; } v; v.f = f;
    uint32_t r = v.u + 0x7fffu + ((v.u >> 16) & 1u);   // RNE
    return (unsigned short)(r >> 16);
}

__device__ __forceinline__ void gload16(const void* g, void* l) {
    __builtin_amdgcn_global_load_lds(
        (__attribute__((address_space(1))) void*)(g),
        (__attribute__((address_space(3))) void*)(l),
        16, 0, 0);
}

// ---------- x [b][k][p] fp32 -> x_t [b][p][k] bf16 ----------
__global__ __launch_bounds__(256)
void k_transpose(const float* __restrict__ x, unsigned short* __restrict__ xt) {
    __shared__ float tile[64][65];
    int bx = blockIdx.x;
    int b = bx >> 10, rem = bx & 1023;
    int k0 = (rem >> 6) << 6, p0 = (rem & 63) << 6;
    int t = threadIdx.x;
    const float* xb = x + ((size_t)b * XCH + k0) * PP + p0;
#pragma unroll
    for (int it = 0; it < 4; ++it) {
        int fi = it * 256 + t;
        int kk = fi >> 4, pp = (fi & 15) << 2;
        float4 v = *(const float4*)(xb + (size_t)kk * PP + pp);
        tile[kk][pp] = v.x; tile[kk][pp + 1] = v.y;
        tile[kk][pp + 2] = v.z; tile[kk][pp + 3] = v.w;
    }
    __syncthreads();
    unsigned short* xtb = xt + ((size_t)b * PP + p0) * XCH + k0;
#pragma unroll
    for (int ot = 0; ot < 2; ++ot) {
        int g = ot * 256 + t;
        int pp = g >> 3, ko = (g & 7) << 3;
        uint32_t u0 = (uint32_t)f2bf(tile[ko + 0][pp]) | ((uint32_t)f2bf(tile[ko + 1][pp]) << 16);
        uint32_t u1 = (uint32_t)f2bf(tile[ko + 2][pp]) | ((uint32_t)f2bf(tile[ko + 3][pp]) << 16);
        uint32_t u2 = (uint32_t)f2bf(tile[ko + 4][pp]) | ((uint32_t)f2bf(tile[ko + 5][pp]) << 16);
        uint32_t u3 = (uint32_t)f2bf(tile[ko + 6][pp]) | ((uint32_t)f2bf(tile[ko + 7][pp]) << 16);
        *(uint4*)(xtb + (size_t)pp * XCH + ko) = make_uint4(u0, u1, u2, u3);
    }
}

// ---------- y_pool[b][c] = mean over HW ----------
__global__ __launch_bounds__(256)
void k_pool(const float* __restrict__ y, float* __restrict__ ypool) {
    int bc = blockIdx.x;
    const float4* base = (const float4*)(y + (size_t)bc * PP);
    int t = threadIdx.x;
    float s = 0.f;
#pragma unroll
    for (int it = 0; it < 4; ++it) {
        float4 v = base[t + it * 256];
        s += v.x + v.y + v.z + v.w;
    }
#pragma unroll
    for (int off = 32; off > 0; off >>= 1) s += __shfl_down(s, off);
    __shared__ float wsum[4];
    if ((t & 63) == 0) wsum[t >> 6] = s;
    __syncthreads();
    if (t == 0) ypool[bc] = (wsum[0] + wsum[1] + wsum[2] + wsum[3]) * (1.f / 4096.f);
}

// ---------- fold BN constants ----------
__global__ void k_consts(const float* g_red, const float* be_red, const float* m_red, const float* v_red, const float* b_red,
                         const float* g_act, const float* be_act, const float* m_act, const float* v_act,
                         const float* g_fus, const float* be_fus, const float* m_fus, const float* v_fus, const float* b_fus,
                         float* A1, float* B1, float* AACT, float* CACT, float* A2, float* B2) {
    int c = threadIdx.x + blockIdx.x * blockDim.x;
    if (c >= CCH) return;
    float a1 = g_red[c] * rsqrtf(v_red[c] + EPSBN);
    A1[c] = a1;
    B1[c] = a1 * (b_red[c] - m_red[c]) + be_red[c];
    float aa = g_act[c] * rsqrtf(v_act[c] + EPSBN);
    AACT[c] = aa;
    CACT[c] = be_act[c] - aa * m_act[c];
    float a2 = g_fus[c] * rsqrtf(v_fus[c] + EPSBN);
    A2[c] = a2;
    B2[c] = a2 * (b_fus[c] - m_fus[c]) + be_fus[c];
}

// ---------- G[b][c] = a_act[c] * relu(bn_gen(w_gen . y_pool + b_gen)) ----------
__global__ __launch_bounds__(256)
void k_gf(const float* __restrict__ wgen, const float* __restrict__ bgen,
          const float* __restrict__ ggen, const float* __restrict__ begen,
          const float* __restrict__ mgen, const float* __restrict__ vgen,
          const float* __restrict__ ypool, const float* __restrict__ AACT,
          float* __restrict__ G) {
    int idx = threadIdx.x + blockIdx.x * 256;
    int b = idx >> 9, c = idx & 511;
    const float4* wr = (const float4*)(wgen + (size_t)c * YCH);
    const float4* yp = (const float4*)(ypool + b * YCH);
    float dot = 0.f;
    for (int k = 0; k < YCH / 4; ++k) {
        float4 w = wr[k], v = yp[k];
        dot += w.x * v.x + w.y * v.y + w.z * v.z + w.w * v.w;
    }
    float ag = ggen[c] * rsqrtf(vgen[c] + EPSBN);
    float gf = fmaxf(ag * (dot + bgen[c] - mgen[c]) + begen[c], 0.f);
    G[idx] = AACT[c] * gf;
}

// ---------- weights fp32 -> bf16 ----------
__global__ __launch_bounds__(256)
void k_cvtw(const float* __restrict__ wred, const float* __restrict__ wfus,
            unsigned short* __restrict__ wred_bf, unsigned short* __restrict__ wfus_bf) {
    int idx = threadIdx.x + blockIdx.x * 256;          // < 196608
    const int n1 = CCH * XCH / 4;                      // 131072
    float4 v; unsigned short* dst;
    if (idx < n1) { v = ((const float4*)wred)[idx]; dst = wred_bf + (size_t)idx * 4; }
    else { int j = idx - n1; v = ((const float4*)wfus)[j]; dst = wfus_bf + (size_t)j * 4; }
    uint32_t lo = (uint32_t)f2bf(v.x) | ((uint32_t)f2bf(v.y) << 16);
    uint32_t hi = (uint32_t)f2bf(v.z) | ((uint32_t)f2bf(v.w) << 16);
    *(uint2*)dst = make_uint2(lo, hi);
}

// ---------- gemm_bt: D[M,N] = A[M,K] x Bt[N,K]^T, bf16 in, fused epilogue ----------
// EPI=0: Out bf16 h[p][c]; consts C0=A1,C1=B1,C2=CACT,C3=G(b).  EPI=1: Out fp32; C0=A2,C1=B2.
template<int KTOT, int EPI>
__global__ __launch_bounds__(256)
void k_gemm(const unsigned short* __restrict__ A, const unsigned short* __restrict__ Bt,
            void* __restrict__ Out,
            const float* __restrict__ C0, const float* __restrict__ C1,
            const float* __restrict__ C2, const float* __restrict__ C3,
            long sAb, long sBb, long sOb, int Ncols) {
    __shared__ __align__(16) unsigned short sA[128 * 64];
    __shared__ __align__(16) unsigned short sB[128 * 64];
    const int tid = threadIdx.x;
    const int lane = tid & 63, wave = tid >> 6;
    const int wr = (wave >> 1) << 6, wc = (wave & 1) << 6;
    const int l15 = lane & 15, l4 = lane >> 4;
    const int swz = (lane & 7) << 4;
    const int m0 = blockIdx.y << 7, n0 = blockIdx.x << 7;
    const int bz = blockIdx.z;

    const unsigned short* Ab = A + (size_t)bz * sAb + (size_t)m0 * KTOT;
    const unsigned short* Bb = Bt + (size_t)bz * sBb + (size_t)n0 * KTOT;

    // staging: linear LDS dest (wave-uniform base + lane*16); inverse-swizzled global source
    int arow[4], akel[4];
#pragma unroll
    for (int q = 0; q < 4; ++q) {
        int o = (wave << 12) + (q << 10) + (lane << 4);
        int row = o >> 7;
        int nat = o ^ ((row & 7) << 4);
        arow[q] = row;
        akel[q] = (nat & 127) >> 1;
    }

    char* sAc = (char*)sA; char* sBc = (char*)sB;

    f32x4 acc[4][4];
#pragma unroll
    for (int i = 0; i < 4; ++i)
#pragma unroll
        for (int j = 0; j < 4; ++j) acc[i][j] = (f32x4){0.f, 0.f, 0.f, 0.f};

    for (int kk = 0; kk < KTOT; kk += 64) {
#pragma unroll
        for (int q = 0; q < 4; ++q)
            gload16(Ab + (size_t)arow[q] * KTOT + kk + akel[q], sAc + (wave << 12) + (q << 10));
#pragma unroll
        for (int q = 0; q < 4; ++q)
            gload16(Bb + (size_t)arow[q] * KTOT + kk + akel[q], sBc + (wave << 12) + (q << 10));
        __syncthreads();
#pragma unroll
        for (int k2 = 0; k2 < 2; ++k2) {
            bf16x8 af[4], bv[4];
#pragma unroll
            for (int i = 0; i < 4; ++i) {
                int off = (((wr + (i << 4) + l15) << 7) + (k2 << 6) + (l4 << 4)) ^ swz;
                af[i] = *(const bf16x8*)(sAc + off);
            }
#pragma unroll
            for (int j = 0; j < 4; ++j) {
                int off = (((wc + (j << 4) + l15) << 7) + (k2 << 6) + (l4 << 4)) ^ swz;
                bv[j] = *(const bf16x8*)(sBc + off);
            }
#pragma unroll
            for (int i = 0; i < 4; ++i)
#pragma unroll
                for (int j = 0; j < 4; ++j)
                    acc[i][j] = __builtin_amdgcn_mfma_f32_16x16x32_bf16(af[i], bv[j], acc[i][j], 0, 0, 0);
        }
        __syncthreads();
    }

    if constexpr (EPI == 0) {
        unsigned short* Ob = (unsigned short*)Out + (size_t)bz * sOb;
        const float* Gb = C3 + (size_t)bz * CCH;
#pragma unroll
        for (int j = 0; j < 4; ++j) {
            int c = n0 + wc + (j << 4) + l15;
            float a1 = C0[c], b1 = C1[c], ca = C2[c], g = Gb[c];
#pragma unroll
            for (int i = 0; i < 4; ++i) {
                int pr = m0 + wr + (i << 4) + (l4 << 2);
#pragma unroll
                for (int q = 0; q < 4; ++q) {
                    float xr = fmaxf(a1 * acc[i][j][q] + b1, 0.f);
                    float hv = fmaxf(g * xr + ca, 0.f);
                    Ob[(size_t)(pr + q) * Ncols + c] = f2bf(hv);
                }
            }
        }
    } else {
        float* Ob = (float*)Out + (size_t)bz * sOb;
#pragma unroll
        for (int i = 0; i < 4; ++i) {
#pragma unroll
            for (int q = 0; q < 4; ++q) {
                int orow = m0 + wr + (i << 4) + (l4 << 2) + q;
                float a2 = C0[orow], b2 = C1[orow];
#pragma unroll
                for (int j = 0; j < 4; ++j) {
                    int pc = n0 + wc + (j << 4) + l15;
                    Ob[(size_t)orow * Ncols + pc] = fmaxf(a2 * acc[i][j][q] + b2, 0.f);
                }
            }
        }
    }
}

extern "C" void kernel_launch(void* const* d_in, const int* in_sizes, int n_in,
                              void* d_out, int out_size, void* d_ws, size_t ws_size,
                              hipStream_t stream) {
    const float* x      = (const float*)d_in[0];
    const float* y      = (const float*)d_in[1];
    const float* w_red  = (const float*)d_in[2];
    const float* b_red  = (const float*)d_in[3];
    const float* g_red  = (const float*)d_in[4];
    const float* be_red = (const float*)d_in[5];
    const float* m_red  = (const float*)d_in[6];
    const float* v_red  = (const float*)d_in[7];
    const float* w_gen  = (const float*)d_in[8];
    const float* b_gen  = (const float*)d_in[9];
    const float* g_gen  = (const float*)d_in[10];
    const float* be_gen = (const float*)d_in[11];
    const float* m_gen  = (const float*)d_in[12];
    const float* v_gen  = (const float*)d_in[13];
    const float* g_act  = (const float*)d_in[14];
    const float* be_act = (const float*)d_in[15];
    const float* m_act  = (const float*)d_in[16];
    const float* v_act  = (const float*)d_in[17];
    const float* w_fus  = (const float*)d_in[18];
    const float* b_fus  = (const float*)d_in[19];
    const float* g_fus  = (const float*)d_in[20];
    const float* be_fus = (const float*)d_in[21];
    const float* m_fus  = (const float*)d_in[22];
    const float* v_fus  = (const float*)d_in[23];

    // workspace layout (bytes)
    const size_t off_xt   = 0;                          // 67108864
    const size_t off_h    = 67108864;                   // 33554432
    const size_t off_wred = 100663296;                  // 1048576
    const size_t off_wfus = 101711872;                  // 524288
    const size_t off_pool = 102236160;                  // 16384
    const size_t off_G    = 102252544;                  // 16384
    const size_t off_cst  = 102268928;                  // 6*2048
    const size_t need     = off_cst + 6 * 2048;
    if (ws_size < need) return;  // fail visibly rather than corrupt

    char* ws = (char*)d_ws;
    unsigned short* xt      = (unsigned short*)(ws + off_xt);
    unsigned short* h       = (unsigned short*)(ws + off_h);
    unsigned short* wred_bf = (unsigned short*)(ws + off_wred);
    unsigned short* wfus_bf = (unsigned short*)(ws + off_wfus);
    float* ypool = (float*)(ws + off_pool);
    float* G     = (float*)(ws + off_G);
    float* A1    = (float*)(ws + off_cst);
    float* B1    = A1 + 512;
    float* AACT  = B1 + 512;
    float* CACT  = AACT + 512;
    float* A2    = CACT + 512;
    float* B2    = A2 + 512;

    k_transpose<<<8192, 256, 0, stream>>>(x, xt);
    k_cvtw<<<768, 256, 0, stream>>>(w_red, w_fus, wred_bf, wfus_bf);
    k_pool<<<4096, 256, 0, stream>>>(y, ypool);
    k_consts<<<2, 256, 0, stream>>>(g_red, be_red, m_red, v_red, b_red,
                                    g_act, be_act, m_act, v_act,
                                    g_fus, be_fus, m_fus, v_fus, b_fus,
                                    A1, B1, AACT, CACT, A2, B2);
    k_gf<<<16, 256, 0, stream>>>(w_gen, b_gen, g_gen, be_gen, m_gen, v_gen, ypool, AACT, G);

    dim3 g1(4, 32, 8);   // N=512/128, M=4096/128, batch
    k_gemm<1024, 0><<<g1, 256, 0, stream>>>(xt, wred_bf, h, A1, B1, CACT, G,
                                            (long)PP * XCH, 0L, (long)PP * CCH, CCH);
    dim3 g2(32, 4, 8);   // N=4096/128, M=512/128, batch
    k_gemm<512, 1><<<g2, 256, 0, stream>>>(wfus_bf, h, d_out, A2, B2, nullptr, nullptr,
                                           0L, (long)PP * CCH, (long)CCH * PP, PP);
}

// Round 2
// 160.834 us; speedup vs baseline: 1.0403x; 1.0403x over previous
//
#include <hip/hip_runtime.h>
#include <hip/hip_bf16.h>
#include <stdint.h>

#define EPSBN 1e-5f

typedef float f32x4 __attribute__((ext_vector_type(4)));
typedef __bf16 bf16x8 __attribute__((ext_vector_type(8)));

#define BB 8
#define XCH 1024
#define YCH 512
#define CCH 512
#define PP  4096   // H*W = 64*64

__device__ __forceinline__ unsigned short f2bf(float f) {
    union { float f; uint32_t u; } v; v.f = f;
    uint32_t r = v.u + 0x7fffu + ((v.u >> 16) & 1u);   // RNE
    return (unsigned short)(r >> 16);
}

__device__ __forceinline__ void gload16(const void* g, void* l) {
    __builtin_amdgcn_global_load_lds(
        (__attribute__((address_space(1))) void*)(g),
        (__attribute__((address_space(3))) void*)(l),
        16, 0, 0);
}

// ---------- x [b][k][p] fp32 -> x_t [b][p][k] bf16 ----------
__global__ __launch_bounds__(256)
void k_transpose(const float* __restrict__ x, unsigned short* __restrict__ xt) {
    __shared__ float tile[64][65];
    int bx = blockIdx.x;
    int b = bx >> 10, rem = bx & 1023;
    int k0 = (rem >> 6) << 6, p0 = (rem & 63) << 6;
    int t = threadIdx.x;
    const float* xb = x + ((size_t)b * XCH + k0) * PP + p0;
#pragma unroll
    for (int it = 0; it < 4; ++it) {
        int fi = it * 256 + t;
        int kk = fi >> 4, pp = (fi & 15) << 2;
        float4 v = *(const float4*)(xb + (size_t)kk * PP + pp);
        tile[kk][pp] = v.x; tile[kk][pp + 1] = v.y;
        tile[kk][pp + 2] = v.z; tile[kk][pp + 3] = v.w;
    }
    __syncthreads();
    unsigned short* xtb = xt + ((size_t)b * PP + p0) * XCH + k0;
#pragma unroll
    for (int ot = 0; ot < 2; ++ot) {
        int g = ot * 256 + t;
        int pp = g >> 3, ko = (g & 7) << 3;
        uint32_t u0 = (uint32_t)f2bf(tile[ko + 0][pp]) | ((uint32_t)f2bf(tile[ko + 1][pp]) << 16);
        uint32_t u1 = (uint32_t)f2bf(tile[ko + 2][pp]) | ((uint32_t)f2bf(tile[ko + 3][pp]) << 16);
        uint32_t u2 = (uint32_t)f2bf(tile[ko + 4][pp]) | ((uint32_t)f2bf(tile[ko + 5][pp]) << 16);
        uint32_t u3 = (uint32_t)f2bf(tile[ko + 6][pp]) | ((uint32_t)f2bf(tile[ko + 7][pp]) << 16);
        *(uint4*)(xtb + (size_t)pp * XCH + ko) = make_uint4(u0, u1, u2, u3);
    }
}

// ---------- y_pool[b][c] = mean over HW ----------
__global__ __launch_bounds__(256)
void k_pool(const float* __restrict__ y, float* __restrict__ ypool) {
    int bc = blockIdx.x;
    const float4* base = (const float4*)(y + (size_t)bc * PP);
    int t = threadIdx.x;
    float s = 0.f;
#pragma unroll
    for (int it = 0; it < 4; ++it) {
        float4 v = base[t + it * 256];
        s += v.x + v.y + v.z + v.w;
    }
#pragma unroll
    for (int off = 32; off > 0; off >>= 1) s += __shfl_down(s, off);
    __shared__ float wsum[4];
    if ((t & 63) == 0) wsum[t >> 6] = s;
    __syncthreads();
    if (t == 0) ypool[bc] = (wsum[0] + wsum[1] + wsum[2] + wsum[3]) * (1.f / 4096.f);
}

// ---------- fold BN constants ----------
__global__ void k_consts(const float* g_red, const float* be_red, const float* m_red, const float* v_red, const float* b_red,
                         const float* g_act, const float* be_act, const float* m_act, const float* v_act,
                         const float* g_fus, const float* be_fus, const float* m_fus, const float* v_fus, const float* b_fus,
                         float* A1, float* B1, float* AACT, float* CACT, float* A2, float* B2) {
    int c = threadIdx.x + blockIdx.x * blockDim.x;
    if (c >= CCH) return;
    float a1 = g_red[c] * rsqrtf(v_red[c] + EPSBN);
    A1[c] = a1;
    B1[c] = a1 * (b_red[c] - m_red[c]) + be_red[c];
    float aa = g_act[c] * rsqrtf(v_act[c] + EPSBN);
    AACT[c] = aa;
    CACT[c] = be_act[c] - aa * m_act[c];
    float a2 = g_fus[c] * rsqrtf(v_fus[c] + EPSBN);
    A2[c] = a2;
    B2[c] = a2 * (b_fus[c] - m_fus[c]) + be_fus[c];
}

// ---------- G[b][c] = a_act[c] * relu(bn_gen(w_gen . y_pool + b_gen)) ----------
__global__ __launch_bounds__(256)
void k_gf(const float* __restrict__ wgen, const float* __restrict__ bgen,
          const float* __restrict__ ggen, const float* __restrict__ begen,
          const float* __restrict__ mgen, const float* __restrict__ vgen,
          const float* __restrict__ ypool, const float* __restrict__ AACT,
          float* __restrict__ G) {
    int idx = threadIdx.x + blockIdx.x * 256;
    int b = idx >> 9, c = idx & 511;
    const float4* wr = (const float4*)(wgen + (size_t)c * YCH);
    const float4* yp = (const float4*)(ypool + b * YCH);
    float dot = 0.f;
    for (int k = 0; k < YCH / 4; ++k) {
        float4 w = wr[k], v = yp[k];
        dot += w.x * v.x + w.y * v.y + w.z * v.z + w.w * v.w;
    }
    float ag = ggen[c] * rsqrtf(vgen[c] + EPSBN);
    float gf = fmaxf(ag * (dot + bgen[c] - mgen[c]) + begen[c], 0.f);
    G[idx] = AACT[c] * gf;
}

// ---------- weights fp32 -> bf16 ----------
__global__ __launch_bounds__(256)
void k_cvtw(const float* __restrict__ wred, const float* __restrict__ wfus,
            unsigned short* __restrict__ wred_bf, unsigned short* __restrict__ wfus_bf) {
    int idx = threadIdx.x + blockIdx.x * 256;          // < 196608
    const int n1 = CCH * XCH / 4;                      // 131072
    float4 v; unsigned short* dst;
    if (idx < n1) { v = ((const float4*)wred)[idx]; dst = wred_bf + (size_t)idx * 4; }
    else { int j = idx - n1; v = ((const float4*)wfus)[j]; dst = wfus_bf + (size_t)j * 4; }
    uint32_t lo = (uint32_t)f2bf(v.x) | ((uint32_t)f2bf(v.y) << 16);
    uint32_t hi = (uint32_t)f2bf(v.z) | ((uint32_t)f2bf(v.w) << 16);
    *(uint2*)dst = make_uint2(lo, hi);
}

// ============================================================================
// 256x256 tile, BK=64, 8-wave, 4-phase/K-tile GEMM with counted vmcnt.
// D[M,N] = A[M,K] x Bt[N,K]^T, bf16 in, fp32 acc, fused epilogue.
// LDS: A = 2buf x 2khalf x [256 rows][32 k] bf16 (64KB), B same (64KB).
// Unit swizzle (16B units, u = 4*row + kgroup): lds unit = u ^ ((u>>2)&7).
// Stage: linear LDS dest, inverse-swizzled global source (rule 21).
// Phases per K-tile t (buf b=t&1):
//  P1: ds A(b,k0,i0-3)+B(b,k0,j0-3); stage A(t+1,k1); bar; 16 MFMA; bar
//  P2: ds A(b,k0,i4-7);              stage B(t+1,k1); bar; 16 MFMA; vmcnt; bar
//  P3: ds A(b,k1,i0-3)+B(b,k1,j0-3); stage A(t+2,k0); bar; 16 MFMA; bar
//  P4: ds A(b,k1,i4-7);              stage B(t+2,k0); bar; 16 MFMA; vmcnt; bar
// vmcnt(8) steady (one-tile-ahead landing proof), tail drains 8->4->0.
// ============================================================================
template<int KTOT, int EPI>
__global__ __launch_bounds__(512, 2)
void k_gemm256(const unsigned short* __restrict__ A, const unsigned short* __restrict__ Bt,
               void* __restrict__ Out,
               const float* __restrict__ C0, const float* __restrict__ C1,
               const float* __restrict__ C2, const float* __restrict__ C3,
               long sAb, long sBb, long sOb, int Ncols) {
    __shared__ __align__(16) char sm[131072];
    constexpr int NT = KTOT / 64;
    constexpr int KB = KTOT * 2;   // row stride bytes

    // ---- XCD-chunked swizzle: 256 blocks -> 32 consecutive tiles per XCD ----
    int r = blockIdx.x + gridDim.x * (blockIdx.y + gridDim.y * blockIdx.z);
    int tb = ((r & 7) << 5) | (r >> 3);
    int nx = gridDim.x, ny = gridDim.y;
    int bx = tb % nx, by = (tb / nx) % ny, bz = tb / (nx * ny);
    const int m0 = by << 8, n0 = bx << 8;

    const int tid = threadIdx.x;
    const int lane = tid & 63, wave = tid >> 6;
    const int l15 = lane & 15, l4v = lane >> 4;
    const int wm = wave >> 2, wn = wave & 3;

    // read-side: swizzled per-lane byte offset within a region
    const int lu = ((((l15 << 2) | l4v) ^ (l15 & 7)) << 4);
    char* const rdA = sm + (wm << 13) + lu;           // + b*32768 + k2*16384 + i*1024
    char* const rdB = sm + 65536 + (wn << 12) + lu;   // + b*32768 + k2*16384 + j*1024

    // stage-side: inverse swizzle on the global source
    const int X = ((lane >> 2) & 6) | (((lane >> 2) ^ (lane >> 4)) & 1);
    const int lx = lane ^ X;
    const int u0 = (wave << 6) + lx;         // q=0 source unit
    const int u1 = 512 + (wave << 6) + lx;   // q=1 source unit

    const char* Ab = (const char*)(A + (size_t)bz * sAb + (size_t)m0 * KTOT);
    const char* Bb = (const char*)(Bt + (size_t)bz * sBb + (size_t)n0 * KTOT);
    const char* pA0 = Ab + (size_t)(u0 >> 2) * KB + ((u0 & 3) << 4);
    const char* pA1 = Ab + (size_t)(u1 >> 2) * KB + ((u1 & 3) << 4);
    const char* pB0 = Bb + (size_t)(u0 >> 2) * KB + ((u0 & 3) << 4);
    const char* pB1 = Bb + (size_t)(u1 >> 2) * KB + ((u1 & 3) << 4);
    char* const stA = sm + (wave << 10);
    char* const stB = sm + 65536 + (wave << 10);

#define STAGE_A(tt, k2) { char* d_ = stA + (((tt) & 1) << 15) + ((k2) << 14); \
        gload16(pA0 + (tt) * 128 + (k2) * 64, d_); \
        gload16(pA1 + (tt) * 128 + (k2) * 64, d_ + 8192); }
#define STAGE_B(tt, k2) { char* d_ = stB + (((tt) & 1) << 15) + ((k2) << 14); \
        gload16(pB0 + (tt) * 128 + (k2) * 64, d_); \
        gload16(pB1 + (tt) * 128 + (k2) * 64, d_ + 8192); }

    f32x4 acc[8][4];
#pragma unroll
    for (int i = 0; i < 8; ++i)
#pragma unroll
        for (int j = 0; j < 4; ++j) acc[i][j] = (f32x4){0.f, 0.f, 0.f, 0.f};

    // ---- prologue: tile0 (k0,k1), tile1 (k0); oldest 4 must land ----
    STAGE_A(0, 0) STAGE_B(0, 0) STAGE_A(0, 1) STAGE_B(0, 1) STAGE_A(1, 0) STAGE_B(1, 0)
    asm volatile("s_waitcnt vmcnt(8)" ::: "memory");
    __builtin_amdgcn_s_barrier();

    for (int tk = 0; tk < NT; ++tk) {
        const int bo = (tk & 1) << 15;
        char* rA = rdA + bo;
        char* rB = rdB + bo;
        bf16x8 aR[4], aS[4], bR[4];

        // ---------------- P1: k0, i0-3 x j0-3 ----------------
#pragma unroll
        for (int i = 0; i < 4; ++i) aR[i] = *(const bf16x8*)(rA + (i << 10));
#pragma unroll
        for (int j = 0; j < 4; ++j) bR[j] = *(const bf16x8*)(rB + (j << 10));
        if (tk + 1 < NT) { STAGE_A(tk + 1, 1) }
        __builtin_amdgcn_s_barrier();
        __builtin_amdgcn_s_setprio(1);
#pragma unroll
        for (int i = 0; i < 4; ++i)
#pragma unroll
            for (int j = 0; j < 4; ++j)
                acc[i][j] = __builtin_amdgcn_mfma_f32_16x16x32_bf16(aR[i], bR[j], acc[i][j], 0, 0, 0);
        __builtin_amdgcn_s_setprio(0);
        __builtin_amdgcn_s_barrier();

        // ---------------- P2: k0, i4-7 x j0-3 ----------------
#pragma unroll
        for (int i = 0; i < 4; ++i) aS[i] = *(const bf16x8*)(rA + 4096 + (i << 10));
        if (tk + 1 < NT) { STAGE_B(tk + 1, 1) }
        __builtin_amdgcn_s_barrier();
        __builtin_amdgcn_s_setprio(1);
#pragma unroll
        for (int i = 0; i < 4; ++i)
#pragma unroll
            for (int j = 0; j < 4; ++j)
                acc[4 + i][j] = __builtin_amdgcn_mfma_f32_16x16x32_bf16(aS[i], bR[j], acc[4 + i][j], 0, 0, 0);
        __builtin_amdgcn_s_setprio(0);
        if (tk < NT - 1) { asm volatile("s_waitcnt vmcnt(8)" ::: "memory"); }
        else             { asm volatile("s_waitcnt vmcnt(0)" ::: "memory"); }
        __builtin_amdgcn_s_barrier();

        // ---------------- P3: k1, i0-3 x j0-3 ----------------
#pragma unroll
        for (int i = 0; i < 4; ++i) aR[i] = *(const bf16x8*)(rA + 16384 + (i << 10));
#pragma unroll
        for (int j = 0; j < 4; ++j) bR[j] = *(const bf16x8*)(rB + 16384 + (j << 10));
        if (tk + 2 < NT) { STAGE_A(tk + 2, 0) }
        __builtin_amdgcn_s_barrier();
        __builtin_amdgcn_s_setprio(1);
#pragma unroll
        for (int i = 0; i < 4; ++i)
#pragma unroll
            for (int j = 0; j < 4; ++j)
                acc[i][j] = __builtin_amdgcn_mfma_f32_16x16x32_bf16(aR[i], bR[j], acc[i][j], 0, 0, 0);
        __builtin_amdgcn_s_setprio(0);
        __builtin_amdgcn_s_barrier();

        // ---------------- P4: k1, i4-7 x j0-3 ----------------
#pragma unroll
        for (int i = 0; i < 4; ++i) aS[i] = *(const bf16x8*)(rA + 16384 + 4096 + (i << 10));
        if (tk + 2 < NT) { STAGE_B(tk + 2, 0) }
        __builtin_amdgcn_s_barrier();
        __builtin_amdgcn_s_setprio(1);
#pragma unroll
        for (int i = 0; i < 4; ++i)
#pragma unroll
            for (int j = 0; j < 4; ++j)
                acc[4 + i][j] = __builtin_amdgcn_mfma_f32_16x16x32_bf16(aS[i], bR[j], acc[4 + i][j], 0, 0, 0);
        __builtin_amdgcn_s_setprio(0);
        if (tk < NT - 2)       { asm volatile("s_waitcnt vmcnt(8)" ::: "memory"); }
        else if (tk == NT - 2) { asm volatile("s_waitcnt vmcnt(4)" ::: "memory"); }
        __builtin_amdgcn_s_barrier();
    }
#undef STAGE_A
#undef STAGE_B

    // ---- epilogue ----
    if constexpr (EPI == 0) {
        unsigned short* Ob = (unsigned short*)Out + (size_t)bz * sOb;
        const float* Gb = C3 + (size_t)bz * CCH;
#pragma unroll
        for (int j = 0; j < 4; ++j) {
            int c = n0 + (wn << 6) + (j << 4) + l15;
            float a1 = C0[c], b1 = C1[c], ca = C2[c], g = Gb[c];
#pragma unroll
            for (int i = 0; i < 8; ++i) {
                int pr = m0 + (wm << 7) + (i << 4) + (l4v << 2);
#pragma unroll
                for (int q = 0; q < 4; ++q) {
                    float xr = fmaxf(a1 * acc[i][j][q] + b1, 0.f);
                    float hv = fmaxf(g * xr + ca, 0.f);
                    Ob[(size_t)(pr + q) * Ncols + c] = f2bf(hv);
                }
            }
        }
    } else {
        float* Ob = (float*)Out + (size_t)bz * sOb;
#pragma unroll
        for (int i = 0; i < 8; ++i) {
#pragma unroll
            for (int q = 0; q < 4; ++q) {
                int orow = m0 + (wm << 7) + (i << 4) + (l4v << 2) + q;
                float a2 = C0[orow], b2 = C1[orow];
#pragma unroll
                for (int j = 0; j < 4; ++j) {
                    int pc = n0 + (wn << 6) + (j << 4) + l15;
                    Ob[(size_t)orow * Ncols + pc] = fmaxf(a2 * acc[i][j][q] + b2, 0.f);
                }
            }
        }
    }
}

extern "C" void kernel_launch(void* const* d_in, const int* in_sizes, int n_in,
                              void* d_out, int out_size, void* d_ws, size_t ws_size,
                              hipStream_t stream) {
    const float* x      = (const float*)d_in[0];
    const float* y      = (const float*)d_in[1];
    const float* w_red  = (const float*)d_in[2];
    const float* b_red  = (const float*)d_in[3];
    const float* g_red  = (const float*)d_in[4];
    const float* be_red = (const float*)d_in[5];
    const float* m_red  = (const float*)d_in[6];
    const float* v_red  = (const float*)d_in[7];
    const float* w_gen  = (const float*)d_in[8];
    const float* b_gen  = (const float*)d_in[9];
    const float* g_gen  = (const float*)d_in[10];
    const float* be_gen = (const float*)d_in[11];
    const float* m_gen  = (const float*)d_in[12];
    const float* v_gen  = (const float*)d_in[13];
    const float* g_act  = (const float*)d_in[14];
    const float* be_act = (const float*)d_in[15];
    const float* m_act  = (const float*)d_in[16];
    const float* v_act  = (const float*)d_in[17];
    const float* w_fus  = (const float*)d_in[18];
    const float* b_fus  = (const float*)d_in[19];
    const float* g_fus  = (const float*)d_in[20];
    const float* be_fus = (const float*)d_in[21];
    const float* m_fus  = (const float*)d_in[22];
    const float* v_fus  = (const float*)d_in[23];

    // workspace layout (bytes)
    const size_t off_xt   = 0;                          // 67108864
    const size_t off_h    = 67108864;                   // 33554432
    const size_t off_wred = 100663296;                  // 1048576
    const size_t off_wfus = 101711872;                  // 524288
    const size_t off_pool = 102236160;                  // 16384
    const size_t off_G    = 102252544;                  // 16384
    const size_t off_cst  = 102268928;                  // 6*2048
    const size_t need     = off_cst + 6 * 2048;
    if (ws_size < need) return;  // fail visibly rather than corrupt

    char* ws = (char*)d_ws;
    unsigned short* xt      = (unsigned short*)(ws + off_xt);
    unsigned short* h       = (unsigned short*)(ws + off_h);
    unsigned short* wred_bf = (unsigned short*)(ws + off_wred);
    unsigned short* wfus_bf = (unsigned short*)(ws + off_wfus);
    float* ypool = (float*)(ws + off_pool);
    float* G     = (float*)(ws + off_G);
    float* A1    = (float*)(ws + off_cst);
    float* B1    = A1 + 512;
    float* AACT  = B1 + 512;
    float* CACT  = AACT + 512;
    float* A2    = CACT + 512;
    float* B2    = A2 + 512;

    k_transpose<<<8192, 256, 0, stream>>>(x, xt);
    k_cvtw<<<768, 256, 0, stream>>>(w_red, w_fus, wred_bf, wfus_bf);
    k_pool<<<4096, 256, 0, stream>>>(y, ypool);
    k_consts<<<2, 256, 0, stream>>>(g_red, be_red, m_red, v_red, b_red,
                                    g_act, be_act, m_act, v_act,
                                    g_fus, be_fus, m_fus, v_fus, b_fus,
                                    A1, B1, AACT, CACT, A2, B2);
    k_gf<<<16, 256, 0, stream>>>(w_gen, b_gen, g_gen, be_gen, m_gen, v_gen, ypool, AACT, G);

    dim3 g1(2, 16, 8);   // N=512/256, M=4096/256, batch
    k_gemm256<1024, 0><<<g1, 512, 0, stream>>>(xt, wred_bf, h, A1, B1, CACT, G,
                                               (long)PP * XCH, 0L, (long)PP * CCH, CCH);
    dim3 g2(16, 2, 8);   // N=4096/256, M=512/256, batch
    k_gemm256<512, 1><<<g2, 512, 0, stream>>>(wfus_bf, h, d_out, A2, B2, nullptr, nullptr,
                                              0L, (long)PP * CCH, (long)CCH * PP, PP);
}

// Round 4
// 131.398 us; speedup vs baseline: 1.2734x; 1.2240x over previous
//
#include <hip/hip_runtime.h>
#include <hip/hip_bf16.h>
#include <stdint.h>

#define EPSBN 1e-5f

typedef float f32x4 __attribute__((ext_vector_type(4)));
typedef __bf16 bf16x8 __attribute__((ext_vector_type(8)));

#define BB 8
#define XCH 1024
#define YCH 512
#define CCH 512
#define PP  4096   // H*W = 64*64

__device__ __forceinline__ unsigned short f2bf(float f) {
    union { float f; uint32_t u; } v; v.f = f;
    uint32_t r = v.u + 0x7fffu + ((v.u >> 16) & 1u);   // RNE
    return (unsigned short)(r >> 16);
}

__device__ __forceinline__ void gload16(const void* g, void* l) {
    __builtin_amdgcn_global_load_lds(
        (__attribute__((address_space(1))) void*)(g),
        (__attribute__((address_space(3))) void*)(l),
        16, 0, 0);
}

// ---------- fused: y_pool (blocks 0..4095) + weight cvt (blocks 4096..4863) ----------
__global__ __launch_bounds__(256)
void k_pre(const float* __restrict__ y, const float* __restrict__ wred, const float* __restrict__ wfus,
           float* __restrict__ ypool, unsigned short* __restrict__ wred_bf, unsigned short* __restrict__ wfus_bf) {
    int bx = blockIdx.x, t = threadIdx.x;
    if (bx < 4096) {
        const float4* base = (const float4*)(y + (size_t)bx * PP);
        float s = 0.f;
#pragma unroll
        for (int it = 0; it < 4; ++it) {
            float4 v = base[t + it * 256];
            s += v.x + v.y + v.z + v.w;
        }
#pragma unroll
        for (int off = 32; off > 0; off >>= 1) s += __shfl_down(s, off);
        __shared__ float wsum[4];
        if ((t & 63) == 0) wsum[t >> 6] = s;
        __syncthreads();
        if (t == 0) ypool[bx] = (wsum[0] + wsum[1] + wsum[2] + wsum[3]) * (1.f / 4096.f);
    } else {
        int idx = (bx - 4096) * 256 + t;                   // < 196608
        const int n1 = CCH * XCH / 4;                      // 131072
        float4 v; unsigned short* dst;
        if (idx < n1) { v = ((const float4*)wred)[idx]; dst = wred_bf + (size_t)idx * 4; }
        else { int j = idx - n1; v = ((const float4*)wfus)[j]; dst = wfus_bf + (size_t)j * 4; }
        uint32_t lo = (uint32_t)f2bf(v.x) | ((uint32_t)f2bf(v.y) << 16);
        uint32_t hi = (uint32_t)f2bf(v.z) | ((uint32_t)f2bf(v.w) << 16);
        *(uint2*)dst = make_uint2(lo, hi);
    }
}

// ---------- fused: G (blocks 0..15) + BN-const folding (blocks 16..17) ----------
__global__ __launch_bounds__(256)
void k_gf2(const float* __restrict__ wgen, const float* __restrict__ bgen,
           const float* __restrict__ ggen, const float* __restrict__ begen,
           const float* __restrict__ mgen, const float* __restrict__ vgen,
           const float* __restrict__ ypool,
           const float* g_red, const float* be_red, const float* m_red, const float* v_red, const float* b_red,
           const float* g_act, const float* be_act, const float* m_act, const float* v_act,
           const float* g_fus, const float* be_fus, const float* m_fus, const float* v_fus, const float* b_fus,
           float* __restrict__ G, float* A1, float* B1, float* CACT, float* A2, float* B2) {
    int bx = blockIdx.x, t = threadIdx.x;
    if (bx < 16) {
        int idx = bx * 256 + t;
        int b = idx >> 9, c = idx & 511;
        const float4* wr = (const float4*)(wgen + (size_t)c * YCH);
        const float4* yp = (const float4*)(ypool + b * YCH);
        float dot = 0.f;
        for (int k = 0; k < YCH / 4; ++k) {
            float4 w = wr[k], v = yp[k];
            dot += w.x * v.x + w.y * v.y + w.z * v.z + w.w * v.w;
        }
        float ag = ggen[c] * rsqrtf(vgen[c] + EPSBN);
        float gf = fmaxf(ag * (dot + bgen[c] - mgen[c]) + begen[c], 0.f);
        float aa = g_act[c] * rsqrtf(v_act[c] + EPSBN);
        G[idx] = aa * gf;
    } else {
        int c = (bx - 16) * 256 + t;
        if (c >= CCH) return;
        float a1 = g_red[c] * rsqrtf(v_red[c] + EPSBN);
        A1[c] = a1;
        B1[c] = a1 * (b_red[c] - m_red[c]) + be_red[c];
        float aa = g_act[c] * rsqrtf(v_act[c] + EPSBN);
        CACT[c] = be_act[c] - aa * m_act[c];
        float a2 = g_fus[c] * rsqrtf(v_fus[c] + EPSBN);
        A2[c] = a2;
        B2[c] = a2 * (b_fus[c] - m_fus[c]) + be_fus[c];
    }
}

// ============================================================================
// GEMM1 with FUSED transpose+convert A-staging.
// h[b][p][c] = epi( sum_k x[b][k][p] * wred[c][k] ), M=p(4096), N=c(512), K=1024.
// A-side: x fp32 [k][p] reg-staged: 4 k-strided float4 loads -> in-reg 4x4
//   transpose -> 4 ds_write_b64 into the XOR-swizzled [row=p][k] LDS layout.
//   grp0 (k-half0) issued P1, written P3; grp1 issued P2, written P4.
// B-side: wred_bf gload16 (linear dest, inverse-swizzled source), issued P2,
//   consumed next tile; single vmcnt(0)+lgkmcnt(0) drain per K-tile at P4 end.
// ============================================================================
__global__ __launch_bounds__(512, 2)
void k_gemm1(const float* __restrict__ X, const unsigned short* __restrict__ Bt,
             unsigned short* __restrict__ H,
             const float* __restrict__ C0, const float* __restrict__ C1,
             const float* __restrict__ C2, const float* __restrict__ G) {
    __shared__ __align__(16) char sm[131072];
    constexpr int NT = 16;         // K-tiles (K=1024, BK=64)
    constexpr int KB = 2048;       // B row stride bytes

    // XCD-chunked swizzle over 256 blocks (nx=2, ny=16, nz=8)
    int r = blockIdx.x + gridDim.x * (blockIdx.y + gridDim.y * blockIdx.z);
    int tb = ((r & 7) << 5) | (r >> 3);
    int bx = tb & 1, by = (tb >> 1) & 15, bz = tb >> 5;
    const int m0 = by << 8, n0 = bx << 8;

    const int tid = threadIdx.x;
    const int lane = tid & 63, wave = tid >> 6;
    const int l15 = lane & 15, l4v = lane >> 4;
    const int wm = wave >> 2, wn = wave & 3;

    // read-side swizzled per-lane byte offset
    const int lu = ((((l15 << 2) | l4v) ^ (l15 & 7)) << 4);
    char* const rdA = sm + (wm << 13) + lu;
    char* const rdB = sm + 65536 + (wn << 12) + lu;

    // B stage: inverse swizzle on global source, linear LDS dest
    const int Xs = ((lane >> 2) & 6) | (((lane >> 2) ^ (lane >> 4)) & 1);
    const int lx = lane ^ Xs;
    const int u0 = (wave << 6) + lx;
    const int u1 = 512 + (wave << 6) + lx;
    const char* Bb = (const char*)(Bt + (size_t)n0 * 1024);
    const char* pB0 = Bb + (size_t)(u0 >> 2) * KB + ((u0 & 3) << 4);
    const char* pB1 = Bb + (size_t)(u1 >> 2) * KB + ((u1 & 3) << 4);
    char* const stB = sm + 65536 + (wave << 10);

#define STAGE_B(tt, k2) { char* d_ = stB + ((((tt) & 1) << 15) | ((k2) << 14)); \
        gload16(pB0 + (tt) * 128 + (k2) * 64, d_); \
        gload16(pB1 + (tt) * 128 + (k2) * 64, d_ + 8192); }

    // A reg-stage params: pq=(l&7)+8w (p-quad), kq=l>>3 (k-quad within half)
    const int pq = (lane & 7) + (wave << 3);
    const int kq = lane >> 3;
    const int rbase = pq << 2;
    const float* xLd = X + (size_t)bz * (XCH * (size_t)PP) + (size_t)(m0 + (pq << 2));

#define ALOAD(P, tt, hf) { \
        const float* p_ = xLd + (size_t)((tt) * 64 + (hf) * 32 + (kq << 2)) * PP; \
        P##0 = *(const float4*)(p_); \
        P##1 = *(const float4*)(p_ + PP); \
        P##2 = *(const float4*)(p_ + 2 * PP); \
        P##3 = *(const float4*)(p_ + 3 * PP); }

#define AWRITE(P, tt, hf) { \
        char* base_ = sm + ((((tt) & 1) << 15) | ((hf) << 14)); \
        _Pragma("unroll") \
        for (int rr = 0; rr < 4; ++rr) { \
            int row_ = rbase + rr; \
            int punit_ = ((row_ << 2) | (kq >> 1)) ^ (row_ & 7); \
            float f0_ = ((const float*)&P##0)[rr], f1_ = ((const float*)&P##1)[rr]; \
            float f2_ = ((const float*)&P##2)[rr], f3_ = ((const float*)&P##3)[rr]; \
            uint32_t lo_ = (uint32_t)f2bf(f0_) | ((uint32_t)f2bf(f1_) << 16); \
            uint32_t hi_ = (uint32_t)f2bf(f2_) | ((uint32_t)f2bf(f3_) << 16); \
            *(uint2*)(base_ + (punit_ << 4) + ((kq & 1) << 3)) = make_uint2(lo_, hi_); \
        } }

    f32x4 acc[8][4];
#pragma unroll
    for (int i = 0; i < 8; ++i)
#pragma unroll
        for (int j = 0; j < 4; ++j) acc[i][j] = (f32x4){0.f, 0.f, 0.f, 0.f};

    float4 sA0, sA1, sA2, sA3, sC0, sC1, sC2, sC3;

    // ---- prologue: tile 0 ----
    ALOAD(sA, 0, 0) ALOAD(sC, 0, 1)
    STAGE_B(0, 0) STAGE_B(0, 1)
    AWRITE(sA, 0, 0) AWRITE(sC, 0, 1)
    asm volatile("s_waitcnt vmcnt(0) lgkmcnt(0)" ::: "memory");
    __builtin_amdgcn_s_barrier();

    for (int tk = 0; tk < NT; ++tk) {
        const int bo = (tk & 1) << 15;
        char* rA = rdA + bo;
        char* rB = rdB + bo;
        bf16x8 aR[4], aS[4], bR[4];
        const bool pf = (tk + 1 < NT);

        // ---------------- P1: k0, i0-3 x j0-3 ----------------
#pragma unroll
        for (int i = 0; i < 4; ++i) aR[i] = *(const bf16x8*)(rA + (i << 10));
#pragma unroll
        for (int j = 0; j < 4; ++j) bR[j] = *(const bf16x8*)(rB + (j << 10));
        if (pf) { ALOAD(sA, tk + 1, 0) }
        __builtin_amdgcn_s_barrier();
        __builtin_amdgcn_s_setprio(1);
#pragma unroll
        for (int i = 0; i < 4; ++i)
#pragma unroll
            for (int j = 0; j < 4; ++j)
                acc[i][j] = __builtin_amdgcn_mfma_f32_16x16x32_bf16(aR[i], bR[j], acc[i][j], 0, 0, 0);
        __builtin_amdgcn_s_setprio(0);
        __builtin_amdgcn_s_barrier();

        // ---------------- P2: k0, i4-7 x j0-3 ----------------
#pragma unroll
        for (int i = 0; i < 4; ++i) aS[i] = *(const bf16x8*)(rA + 4096 + (i << 10));
        if (pf) { ALOAD(sC, tk + 1, 1) STAGE_B(tk + 1, 0) STAGE_B(tk + 1, 1) }
        __builtin_amdgcn_s_barrier();
        __builtin_amdgcn_s_setprio(1);
#pragma unroll
        for (int i = 0; i < 4; ++i)
#pragma unroll
            for (int j = 0; j < 4; ++j)
                acc[4 + i][j] = __builtin_amdgcn_mfma_f32_16x16x32_bf16(aS[i], bR[j], acc[4 + i][j], 0, 0, 0);
        __builtin_amdgcn_s_setprio(0);
        __builtin_amdgcn_s_barrier();

        // ---------------- P3: k1, i0-3 x j0-3 ----------------
#pragma unroll
        for (int i = 0; i < 4; ++i) aR[i] = *(const bf16x8*)(rA + 16384 + (i << 10));
#pragma unroll
        for (int j = 0; j < 4; ++j) bR[j] = *(const bf16x8*)(rB + 16384 + (j << 10));
        if (pf) { AWRITE(sA, tk + 1, 0) }
        __builtin_amdgcn_s_barrier();
        __builtin_amdgcn_s_setprio(1);
#pragma unroll
        for (int i = 0; i < 4; ++i)
#pragma unroll
            for (int j = 0; j < 4; ++j)
                acc[i][j] = __builtin_amdgcn_mfma_f32_16x16x32_bf16(aR[i], bR[j], acc[i][j], 0, 0, 0);
        __builtin_amdgcn_s_setprio(0);
        __builtin_amdgcn_s_barrier();

        // ---------------- P4: k1, i4-7 x j0-3 ----------------
#pragma unroll
        for (int i = 0; i < 4; ++i) aS[i] = *(const bf16x8*)(rA + 16384 + 4096 + (i << 10));
        if (pf) { AWRITE(sC, tk + 1, 1) }
        __builtin_amdgcn_s_barrier();
        __builtin_amdgcn_s_setprio(1);
#pragma unroll
        for (int i = 0; i < 4; ++i)
#pragma unroll
            for (int j = 0; j < 4; ++j)
                acc[4 + i][j] = __builtin_amdgcn_mfma_f32_16x16x32_bf16(aS[i], bR[j], acc[4 + i][j], 0, 0, 0);
        __builtin_amdgcn_s_setprio(0);
        asm volatile("s_waitcnt vmcnt(0) lgkmcnt(0)" ::: "memory");
        __builtin_amdgcn_s_barrier();
    }
#undef STAGE_B
#undef ALOAD
#undef AWRITE

    // ---- epilogue: relu(bn_red) * G + CACT, relu, -> bf16 h[p][c] ----
    unsigned short* Ob = H + (size_t)bz * ((size_t)PP * CCH);
    const float* Gb = G + (size_t)bz * CCH;
#pragma unroll
    for (int j = 0; j < 4; ++j) {
        int c = n0 + (wn << 6) + (j << 4) + l15;
        float a1 = C0[c], b1 = C1[c], ca = C2[c], g = Gb[c];
#pragma unroll
        for (int i = 0; i < 8; ++i) {
            int pr = m0 + (wm << 7) + (i << 4) + (l4v << 2);
#pragma unroll
            for (int q = 0; q < 4; ++q) {
                float xr = fmaxf(a1 * acc[i][j][q] + b1, 0.f);
                float hv = fmaxf(g * xr + ca, 0.f);
                Ob[(size_t)(pr + q) * CCH + c] = f2bf(hv);
            }
        }
    }
}

// ============================================================================
// GEMM2 (round-2 structure, verified): out[b][c][p] = relu(bn_fus(wfus . h))
// A = wfus_bf [512 c][512 k], B = h [b][4096 p][512 k], fp32 out.
// ============================================================================
__global__ __launch_bounds__(512, 2)
void k_gemm2(const unsigned short* __restrict__ A, const unsigned short* __restrict__ Bt,
             float* __restrict__ Out,
             const float* __restrict__ C0, const float* __restrict__ C1) {
    __shared__ __align__(16) char sm[131072];
    constexpr int NT = 8;          // K=512, BK=64
    constexpr int KB = 1024;       // row stride bytes

    // swizzle: nx=16, ny=2, nz=8
    int r = blockIdx.x + gridDim.x * (blockIdx.y + gridDim.y * blockIdx.z);
    int tb = ((r & 7) << 5) | (r >> 3);
    int bx = tb & 15, by = (tb >> 4) & 1, bz = tb >> 5;
    const int m0 = by << 8, n0 = bx << 8;

    const int tid = threadIdx.x;
    const int lane = tid & 63, wave = tid >> 6;
    const int l15 = lane & 15, l4v = lane >> 4;
    const int wm = wave >> 2, wn = wave & 3;

    const int lu = ((((l15 << 2) | l4v) ^ (l15 & 7)) << 4);
    char* const rdA = sm + (wm << 13) + lu;
    char* const rdB = sm + 65536 + (wn << 12) + lu;

    const int X = ((lane >> 2) & 6) | (((lane >> 2) ^ (lane >> 4)) & 1);
    const int lx = lane ^ X;
    const int u0 = (wave << 6) + lx;
    const int u1 = 512 + (wave << 6) + lx;

    const char* Ab = (const char*)(A + (size_t)m0 * 512);
    const char* Bb = (const char*)(Bt + (size_t)bz * ((size_t)PP * CCH) + (size_t)n0 * 512);
    const char* pA0 = Ab + (size_t)(u0 >> 2) * KB + ((u0 & 3) << 4);
    const char* pA1 = Ab + (size_t)(u1 >> 2) * KB + ((u1 & 3) << 4);
    const char* pB0 = Bb + (size_t)(u0 >> 2) * KB + ((u0 & 3) << 4);
    const char* pB1 = Bb + (size_t)(u1 >> 2) * KB + ((u1 & 3) << 4);
    char* const stA = sm + (wave << 10);
    char* const stB = sm + 65536 + (wave << 10);

#define STAGE_A(tt, k2) { char* d_ = stA + ((((tt) & 1) << 15) | ((k2) << 14)); \
        gload16(pA0 + (tt) * 128 + (k2) * 64, d_); \
        gload16(pA1 + (tt) * 128 + (k2) * 64, d_ + 8192); }
#define STAGE_B(tt, k2) { char* d_ = stB + ((((tt) & 1) << 15) | ((k2) << 14)); \
        gload16(pB0 + (tt) * 128 + (k2) * 64, d_); \
        gload16(pB1 + (tt) * 128 + (k2) * 64, d_ + 8192); }

    f32x4 acc[8][4];
#pragma unroll
    for (int i = 0; i < 8; ++i)
#pragma unroll
        for (int j = 0; j < 4; ++j) acc[i][j] = (f32x4){0.f, 0.f, 0.f, 0.f};

    STAGE_A(0, 0) STAGE_B(0, 0) STAGE_A(0, 1) STAGE_B(0, 1) STAGE_A(1, 0) STAGE_B(1, 0)
    asm volatile("s_waitcnt vmcnt(8)" ::: "memory");
    __builtin_amdgcn_s_barrier();

    for (int tk = 0; tk < NT; ++tk) {
        const int bo = (tk & 1) << 15;
        char* rA = rdA + bo;
        char* rB = rdB + bo;
        bf16x8 aR[4], aS[4], bR[4];

        // P1
#pragma unroll
        for (int i = 0; i < 4; ++i) aR[i] = *(const bf16x8*)(rA + (i << 10));
#pragma unroll
        for (int j = 0; j < 4; ++j) bR[j] = *(const bf16x8*)(rB + (j << 10));
        if (tk + 1 < NT) { STAGE_A(tk + 1, 1) }
        __builtin_amdgcn_s_barrier();
        __builtin_amdgcn_s_setprio(1);
#pragma unroll
        for (int i = 0; i < 4; ++i)
#pragma unroll
            for (int j = 0; j < 4; ++j)
                acc[i][j] = __builtin_amdgcn_mfma_f32_16x16x32_bf16(aR[i], bR[j], acc[i][j], 0, 0, 0);
        __builtin_amdgcn_s_setprio(0);
        __builtin_amdgcn_s_barrier();

        // P2
#pragma unroll
        for (int i = 0; i < 4; ++i) aS[i] = *(const bf16x8*)(rA + 4096 + (i << 10));
        if (tk + 1 < NT) { STAGE_B(tk + 1, 1) }
        __builtin_amdgcn_s_barrier();
        __builtin_amdgcn_s_setprio(1);
#pragma unroll
        for (int i = 0; i < 4; ++i)
#pragma unroll
            for (int j = 0; j < 4; ++j)
                acc[4 + i][j] = __builtin_amdgcn_mfma_f32_16x16x32_bf16(aS[i], bR[j], acc[4 + i][j], 0, 0, 0);
        __builtin_amdgcn_s_setprio(0);
        if (tk < NT - 1) { asm volatile("s_waitcnt vmcnt(8)" ::: "memory"); }
        else             { asm volatile("s_waitcnt vmcnt(0)" ::: "memory"); }
        __builtin_amdgcn_s_barrier();

        // P3
#pragma unroll
        for (int i = 0; i < 4; ++i) aR[i] = *(const bf16x8*)(rA + 16384 + (i << 10));
#pragma unroll
        for (int j = 0; j < 4; ++j) bR[j] = *(const bf16x8*)(rB + 16384 + (j << 10));
        if (tk + 2 < NT) { STAGE_A(tk + 2, 0) }
        __builtin_amdgcn_s_barrier();
        __builtin_amdgcn_s_setprio(1);
#pragma unroll
        for (int i = 0; i < 4; ++i)
#pragma unroll
            for (int j = 0; j < 4; ++j)
                acc[i][j] = __builtin_amdgcn_mfma_f32_16x16x32_bf16(aR[i], bR[j], acc[i][j], 0, 0, 0);
        __builtin_amdgcn_s_setprio(0);
        __builtin_amdgcn_s_barrier();

        // P4
#pragma unroll
        for (int i = 0; i < 4; ++i) aS[i] = *(const bf16x8*)(rA + 16384 + 4096 + (i << 10));
        if (tk + 2 < NT) { STAGE_B(tk + 2, 0) }
        __builtin_amdgcn_s_barrier();
        __builtin_amdgcn_s_setprio(1);
#pragma unroll
        for (int i = 0; i < 4; ++i)
#pragma unroll
            for (int j = 0; j < 4; ++j)
                acc[4 + i][j] = __builtin_amdgcn_mfma_f32_16x16x32_bf16(aS[i], bR[j], acc[4 + i][j], 0, 0, 0);
        __builtin_amdgcn_s_setprio(0);
        if (tk < NT - 2)       { asm volatile("s_waitcnt vmcnt(8)" ::: "memory"); }
        else if (tk == NT - 2) { asm volatile("s_waitcnt vmcnt(4)" ::: "memory"); }
        __builtin_amdgcn_s_barrier();
    }
#undef STAGE_A
#undef STAGE_B

    // epilogue: fp32 out, BN_fus + ReLU
    float* Ob = Out + (size_t)bz * ((size_t)CCH * PP);
#pragma unroll
    for (int i = 0; i < 8; ++i) {
#pragma unroll
        for (int q = 0; q < 4; ++q) {
            int orow = m0 + (wm << 7) + (i << 4) + (l4v << 2) + q;
            float a2 = C0[orow], b2 = C1[orow];
#pragma unroll
            for (int j = 0; j < 4; ++j) {
                int pc = n0 + (wn << 6) + (j << 4) + l15;
                Ob[(size_t)orow * PP + pc] = fmaxf(a2 * acc[i][j][q] + b2, 0.f);
            }
        }
    }
}

extern "C" void kernel_launch(void* const* d_in, const int* in_sizes, int n_in,
                              void* d_out, int out_size, void* d_ws, size_t ws_size,
                              hipStream_t stream) {
    const float* x      = (const float*)d_in[0];
    const float* y      = (const float*)d_in[1];
    const float* w_red  = (const float*)d_in[2];
    const float* b_red  = (const float*)d_in[3];
    const float* g_red  = (const float*)d_in[4];
    const float* be_red = (const float*)d_in[5];
    const float* m_red  = (const float*)d_in[6];
    const float* v_red  = (const float*)d_in[7];
    const float* w_gen  = (const float*)d_in[8];
    const float* b_gen  = (const float*)d_in[9];
    const float* g_gen  = (const float*)d_in[10];
    const float* be_gen = (const float*)d_in[11];
    const float* m_gen  = (const float*)d_in[12];
    const float* v_gen  = (const float*)d_in[13];
    const float* g_act  = (const float*)d_in[14];
    const float* be_act = (const float*)d_in[15];
    const float* m_act  = (const float*)d_in[16];
    const float* v_act  = (const float*)d_in[17];
    const float* w_fus  = (const float*)d_in[18];
    const float* b_fus  = (const float*)d_in[19];
    const float* g_fus  = (const float*)d_in[20];
    const float* be_fus = (const float*)d_in[21];
    const float* m_fus  = (const float*)d_in[22];
    const float* v_fus  = (const float*)d_in[23];

    // workspace layout (bytes) — xt slot retired, offsets kept stable
    const size_t off_h    = 67108864;                   // 33554432
    const size_t off_wred = 100663296;                  // 1048576
    const size_t off_wfus = 101711872;                  // 524288
    const size_t off_pool = 102236160;                  // 16384
    const size_t off_G    = 102252544;                  // 16384
    const size_t off_cst  = 102268928;                  // 6*2048
    const size_t need     = off_cst + 6 * 2048;
    if (ws_size < need) return;

    char* ws = (char*)d_ws;
    unsigned short* h       = (unsigned short*)(ws + off_h);
    unsigned short* wred_bf = (unsigned short*)(ws + off_wred);
    unsigned short* wfus_bf = (unsigned short*)(ws + off_wfus);
    float* ypool = (float*)(ws + off_pool);
    float* G     = (float*)(ws + off_G);
    float* A1    = (float*)(ws + off_cst);
    float* B1    = A1 + 512;
    float* CACT  = B1 + 512;
    float* A2    = CACT + 512;
    float* B2    = A2 + 512;

    k_pre<<<4864, 256, 0, stream>>>(y, w_red, w_fus, ypool, wred_bf, wfus_bf);
    k_gf2<<<18, 256, 0, stream>>>(w_gen, b_gen, g_gen, be_gen, m_gen, v_gen, ypool,
                                  g_red, be_red, m_red, v_red, b_red,
                                  g_act, be_act, m_act, v_act,
                                  g_fus, be_fus, m_fus, v_fus, b_fus,
                                  G, A1, B1, CACT, A2, B2);

    dim3 g1(2, 16, 8);   // N=512/256, M=4096/256, batch
    k_gemm1<<<g1, 512, 0, stream>>>(x, wred_bf, h, A1, B1, CACT, G);
    dim3 g2(16, 2, 8);   // N=4096/256, M=512/256, batch
    k_gemm2<<<g2, 512, 0, stream>>>(wfus_bf, h, (float*)d_out, A2, B2);
}